// Round 11
// baseline (346.607 us; speedup 1.0000x reference)
//
#include <hip/hip_runtime.h>
#include <hip/hip_bf16.h>

#define H_DIM 2048
#define T_TOK 2048
#define E_NUM 16
#define I_DIM 1024
#define TOPK  4
#define NK1   32   // H_DIM/64
#define NK2   16   // I_DIM/64
#define MBMAX 48   // Sum ceil(cnt_e/256) <= 16 + 8192/256

typedef short short8v __attribute__((ext_vector_type(8)));
typedef float f32x4v __attribute__((ext_vector_type(4)));
typedef unsigned short u16;
typedef unsigned int u32;

// ---------- ws layout (bytes) ----------
constexpr size_t OFF_XB   = 0;                                     // 8 MiB
constexpr size_t OFF_ABUF = OFF_XB   + (size_t)T_TOK*H_DIM*2;      // 16 MiB
constexpr size_t OFF_SEL  = OFF_ABUF + (size_t)T_TOK*TOPK*I_DIM*2;
constexpr size_t OFF_WTS  = OFF_SEL  + (size_t)T_TOK*TOPK*4;
constexpr size_t OFF_CNT  = OFF_WTS  + (size_t)T_TOK*TOPK*4;
constexpr size_t OFF_OFFS = OFF_CNT  + 128;
constexpr size_t OFF_CURS = OFF_OFFS + 128;
constexpr size_t OFF_RTOK = OFF_CURS + 128;
constexpr size_t OFF_RWT  = OFF_RTOK + (size_t)T_TOK*TOPK*4;
constexpr size_t OFF_MBE  = OFF_RWT  + (size_t)T_TOK*TOPK*4;
constexpr size_t OFF_MBM0 = OFF_MBE  + 256;
constexpr size_t OFF_MBN  = OFF_MBM0 + 256;
constexpr size_t WS_NEED  = OFF_MBN  + 128;

// ---------- helpers ----------
__device__ __forceinline__ u16 f2b(float f) {   // fp32 -> bf16 RNE
  u32 u = __builtin_bit_cast(u32, f);
  u32 r = (u + 0x7FFFu + ((u >> 16) & 1u)) >> 16;
  return (u16)r;
}

__device__ __forceinline__ u32 cvtpk(float lo, float hi) {
  u32 r;
  asm("v_cvt_pk_bf16_f32 %0, %1, %2" : "=v"(r) : "v"(lo), "v"(hi));
  return r;
}

__device__ __forceinline__ void gld16(const void* g, void* l) {
  __builtin_amdgcn_global_load_lds(
      (const __attribute__((address_space(1))) u32*)g,
      (__attribute__((address_space(3))) u32*)l, 16, 0, 0);
}

// ---------- fp32 -> bf16 (x) ----------
__global__ __launch_bounds__(256) void cvt_x_kernel(const float* __restrict__ src,
                                                    u16* __restrict__ dst) {
  int i = blockIdx.x * 256 + threadIdx.x;
  const float4* s = (const float4*)src + (size_t)i * 2;
  float4 a = s[0], b = s[1];
  uint4 o;
  o.x = (u32)f2b(a.x) | ((u32)f2b(a.y) << 16);
  o.y = (u32)f2b(a.z) | ((u32)f2b(a.w) << 16);
  o.z = (u32)f2b(b.x) | ((u32)f2b(b.y) << 16);
  o.w = (u32)f2b(b.z) | ((u32)f2b(b.w) << 16);
  ((uint4*)dst)[i] = o;
}

// ---------- router ----------
__global__ __launch_bounds__(256) void router_kernel(const float* __restrict__ x,
                                                     const float* __restrict__ rw,
                                                     float* __restrict__ logits,
                                                     int* __restrict__ sel,
                                                     float* __restrict__ wts) {
  int w = threadIdx.x >> 6, lane = threadIdx.x & 63;
  int t = blockIdx.x * 4 + w;

  const float4* xt = (const float4*)(x + (size_t)t * H_DIM);
  float4 xv[8];
  #pragma unroll
  for (int j = 0; j < 8; ++j) xv[j] = xt[j * 64 + lane];

  const float4* rw4 = (const float4*)rw;
  float le[E_NUM];
  #pragma unroll
  for (int e = 0; e < E_NUM; ++e) {
    float s = 0.f;
    #pragma unroll
    for (int j = 0; j < 8; ++j) {
      float4 wv = rw4[e * (H_DIM / 4) + j * 64 + lane];
      s += xv[j].x * wv.x + xv[j].y * wv.y + xv[j].z * wv.z + xv[j].w * wv.w;
    }
    #pragma unroll
    for (int off = 32; off; off >>= 1) s += __shfl_xor(s, off);
    le[e] = s;
  }

  int taken = 0;
  float tv[TOPK]; int ti[TOPK];
  #pragma unroll
  for (int k = 0; k < TOPK; ++k) {
    float bv = -1e30f; int bi = 0;
    #pragma unroll
    for (int e = 0; e < E_NUM; ++e) {
      bool ok = !(taken & (1 << e));
      if (ok && le[e] > bv) { bv = le[e]; bi = e; }
    }
    taken |= (1 << bi); tv[k] = bv; ti[k] = bi;
  }
  float m = tv[0];
  float ew[TOPK]; float ssum = 0.f;
  #pragma unroll
  for (int k = 0; k < TOPK; ++k) { ew[k] = __expf(tv[k] - m); ssum += ew[k]; }
  if (lane == 0) {
    #pragma unroll
    for (int e = 0; e < E_NUM; ++e) logits[(size_t)t * E_NUM + e] = le[e];
    float inv = 1.f / ssum;
    #pragma unroll
    for (int k = 0; k < TOPK; ++k) {
      sel[t * TOPK + k] = ti[k];
      wts[t * TOPK + k] = ew[k] * inv;
    }
  }
}

// ---------- grouping ----------
__global__ void hist_kernel(const int* __restrict__ sel, int* __restrict__ cnt) {
  int p = blockIdx.x * 256 + threadIdx.x;
  if (p < T_TOK * TOPK) atomicAdd(&cnt[sel[p]], 1);
}

__global__ void prefix_kernel(const int* __restrict__ cnt, int* __restrict__ offs,
                              int* __restrict__ curs, int* __restrict__ mbe,
                              int* __restrict__ mbm0, int* __restrict__ mbn) {
  if (threadIdx.x == 0) {
    int a = 0;
    for (int e = 0; e < E_NUM; ++e) { offs[e] = a; curs[e] = a; a += cnt[e]; }
    offs[E_NUM] = a;
    int nb = 0;
    for (int e = 0; e < E_NUM; ++e)
      for (int m0 = 0; m0 < cnt[e]; m0 += 256) {
        mbe[nb] = e; mbm0[nb] = m0; ++nb;
      }
    mbn[0] = nb;
  }
}

__global__ void scatter_kernel(const int* __restrict__ sel, const float* __restrict__ wts,
                               int* __restrict__ curs, int* __restrict__ rtok,
                               float* __restrict__ rwt) {
  int p = blockIdx.x * 256 + threadIdx.x;
  if (p >= T_TOK * TOPK) return;
  int e = sel[p];
  int pos = atomicAdd(&curs[e], 1);
  rtok[pos] = p >> 2;
  rwt[pos] = wts[p];
}

// ================= GEMM1: x @ [gate ; up] -> silu(g)*u*wt -> abuf (bf16) ==========
// 256M x 64 I-cols (128 B-LDS rows: [0:64)=gate, [64:128)=up). BK=64, 256 thr,
// 4 waves 2m x 2n, WAVE TILE 128x64 (acc[8][4]) -> LDS-read bytes/FLOP halved
// vs 64x64 (the R1-R10 binding constraint: ds_read_b128 ~85 B/cy/CU shared).
__global__ __launch_bounds__(256, 2) void gemm1k(
    const u16* __restrict__ xb, const float* __restrict__ wg, const float* __restrict__ wu,
    const int* __restrict__ cnt, const int* __restrict__ offs,
    const int* __restrict__ rtok, const float* __restrict__ rwt,
    const int* __restrict__ mbe, const int* __restrict__ mbm0,
    const int* __restrict__ mbn, u16* __restrict__ abuf) {
  int mb = blockIdx.y;
  if (mb >= mbn[0]) return;
  int e = mbe[mb];
  int m0 = mbm0[mb];
  int cntE = cnt[e];
  int n0 = blockIdx.x * 64;     // 64 I-cols (gate & up)
  int base = offs[e];

  __shared__ alignas(16) char As[32768];   // 256 rows x 64k bf16
  __shared__ alignas(16) char Bs[16384];   // 128 rows x 64k bf16

  int tid = threadIdx.x;
  int lane = tid & 63;
  int w = tid >> 6;              // 0..3
  int wr = (w >> 1) * 128;       // M half (128 rows per wave)
  int wc = w & 1;                // 32-col half
  int ln15 = lane & 15, g4 = lane >> 4;

  // ---- A staging: 8 x gld16/thread (rows 0..255, 8 slots/row, ^(row&7)) ----
  const u16* aptr[8]; int soff[8];
  #pragma unroll
  for (int it = 0; it < 8; ++it) {
    int s = it * 256 + tid;
    int row = s >> 3;
    int p = m0 + row;
    int pp = (p < cntE) ? p : (cntE - 1);
    int tok = rtok[base + pp];
    int c16 = (s & 7) ^ (row & 7);
    soff[it] = s * 16;
    aptr[it] = xb + (size_t)tok * H_DIM + c16 * 8;
  }

  // ---- B staging: thread = (cg: 4 rows, kg: 8 ks). LDS row<64 gate, >=64 up ----
  int cg = tid & 31, kg = tid >> 5;       // kg 0..7
  const float* bmat = (cg < 16) ? wg : wu;
  const float* bsrc = bmat + (size_t)e * H_DIM * I_DIM + n0 + (cg & 15) * 4;
  int bwb[4];
  #pragma unroll
  for (int ii = 0; ii < 4; ++ii) {
    int row = cg * 4 + ii;
    bwb[ii] = row * 128 + ((kg ^ ((row ^ (row >> 2)) & 7)) << 4);
  }

  // ---- fragment read offsets ----
  int aoff[8];
  #pragma unroll
  for (int m = 0; m < 8; ++m) aoff[m] = (wr + m * 16 + ln15) * 128;
  int bro[4], bsz[4];
  #pragma unroll
  for (int n = 0; n < 4; ++n) {
    int brow = ((n < 2) ? (wc * 32 + n * 16) : (64 + wc * 32 + (n - 2) * 16)) + ln15;
    bro[n] = brow * 128;
    bsz[n] = ((brow ^ (brow >> 2)) & 7) << 4;
  }
  int la7_4 = (lane & 7) << 4;

  f32x4v acc[8][4];
  #pragma unroll
  for (int m = 0; m < 8; ++m)
    #pragma unroll
    for (int n = 0; n < 4; ++n) acc[m][n] = f32x4v{0, 0, 0, 0};

  #pragma unroll 1
  for (int kb = 0; kb < NK1; ++kb) {
    // stage A (direct to LDS)
    #pragma unroll
    for (int it = 0; it < 8; ++it)
      gld16(aptr[it] + (size_t)kb * 64, As + soff[it]);
    // stage B: 8 float4 (4 cols x 8 ks), cvtpk pairs, 4 x ds_write_b128
    {
      const float* p0 = bsrc + (size_t)(kb * 64 + kg * 8) * I_DIM;
      float4 f[8];
      #pragma unroll
      for (int r = 0; r < 8; ++r) f[r] = *(const float4*)(p0 + (size_t)r * I_DIM);
      #pragma unroll
      for (int ii = 0; ii < 4; ++ii) {
        uint4 v;
        v.x = cvtpk((&f[0].x)[ii], (&f[1].x)[ii]);
        v.y = cvtpk((&f[2].x)[ii], (&f[3].x)[ii]);
        v.z = cvtpk((&f[4].x)[ii], (&f[5].x)[ii]);
        v.w = cvtpk((&f[6].x)[ii], (&f[7].x)[ii]);
        *(uint4*)(Bs + bwb[ii]) = v;
      }
    }
    __syncthreads();
    #pragma unroll
    for (int kk = 0; kk < 2; ++kk) {
      int xo = (kk * 4 + g4) << 4;
      short8v b[4];
      #pragma unroll
      for (int n = 0; n < 4; ++n)
        b[n] = *(const short8v*)(Bs + bro[n] + (xo ^ bsz[n]));
      #pragma unroll
      for (int m = 0; m < 8; ++m) {
        short8v a = *(const short8v*)(As + aoff[m] + (xo ^ la7_4));
        #pragma unroll
        for (int n = 0; n < 4; ++n)
          acc[m][n] = __builtin_amdgcn_mfma_f32_16x16x32_bf16(a, b[n], acc[m][n], 0, 0, 0);
      }
    }
    __syncthreads();
  }

  // epilogue: acc[m][j]=gate, acc[m][j+2]=up for col n0 + wc*32 + j*16 + ln15
  #pragma unroll
  for (int m = 0; m < 8; ++m) {
    #pragma unroll
    for (int r = 0; r < 4; ++r) {
      int row = wr + m * 16 + g4 * 4 + r;
      if (m0 + row < cntE) {
        float wt = rwt[base + m0 + row];
        size_t orow = (size_t)(base + m0 + row) * I_DIM + n0 + wc * 32;
        #pragma unroll
        for (int j = 0; j < 2; ++j) {
          float g = acc[m][j][r], u = acc[m][j + 2][r];
          float aa = g / (1.f + __expf(-g)) * u * wt;
          abuf[orow + j * 16 + ln15] = f2b(aa);
        }
      }
    }
  }
}

// ================= GEMM2: abuf @ w_down -> atomic-add into out (f32) ==============
// 256M x 128 H-cols, BK=64, 4 waves, wave tile 128x64 (acc[8][4]).
__global__ __launch_bounds__(256, 2) void gemm2k(
    const u16* __restrict__ abuf, const float* __restrict__ wd,
    const int* __restrict__ cnt, const int* __restrict__ offs,
    const int* __restrict__ rtok,
    const int* __restrict__ mbe, const int* __restrict__ mbm0,
    const int* __restrict__ mbn, float* __restrict__ out) {
  int mb = blockIdx.y;
  if (mb >= mbn[0]) return;
  int e = mbe[mb];
  int m0 = mbm0[mb];
  int cntE = cnt[e];
  int n0 = blockIdx.x * 128;    // 128 H-cols
  int base = offs[e];

  __shared__ alignas(16) char As[32768];
  __shared__ alignas(16) char Bs[16384];

  int tid = threadIdx.x;
  int lane = tid & 63;
  int w = tid >> 6;
  int wr = (w >> 1) * 128;
  int wc = w & 1;
  int ln15 = lane & 15, g4 = lane >> 4;

  const u16* aptr[8]; int soff[8];
  #pragma unroll
  for (int it = 0; it < 8; ++it) {
    int s = it * 256 + tid;
    int row = s >> 3;
    int p = m0 + row;
    int pp = (p < cntE) ? p : (cntE - 1);
    int c16 = (s & 7) ^ (row & 7);
    soff[it] = s * 16;
    aptr[it] = abuf + (size_t)(base + pp) * I_DIM + c16 * 8;
  }

  // B staging: LDS rows 0..127 = H-cols n0..+127
  int cg = tid & 31, kg = tid >> 5;
  const float* bsrc = wd + (size_t)e * I_DIM * H_DIM + n0 + cg * 4;
  int bwb[4];
  #pragma unroll
  for (int ii = 0; ii < 4; ++ii) {
    int row = cg * 4 + ii;
    bwb[ii] = row * 128 + ((kg ^ ((row ^ (row >> 2)) & 7)) << 4);
  }

  int aoff[8];
  #pragma unroll
  for (int m = 0; m < 8; ++m) aoff[m] = (wr + m * 16 + ln15) * 128;
  int bro[4], bsz[4];
  #pragma unroll
  for (int n = 0; n < 4; ++n) {
    int brow = wc * 64 + n * 16 + ln15;
    bro[n] = brow * 128;
    bsz[n] = ((brow ^ (brow >> 2)) & 7) << 4;
  }
  int la7_4 = (lane & 7) << 4;

  f32x4v acc[8][4];
  #pragma unroll
  for (int m = 0; m < 8; ++m)
    #pragma unroll
    for (int n = 0; n < 4; ++n) acc[m][n] = f32x4v{0, 0, 0, 0};

  #pragma unroll 1
  for (int kb = 0; kb < NK2; ++kb) {
    #pragma unroll
    for (int it = 0; it < 8; ++it)
      gld16(aptr[it] + (size_t)kb * 64, As + soff[it]);
    {
      const float* p0 = bsrc + (size_t)(kb * 64 + kg * 8) * H_DIM;
      float4 f[8];
      #pragma unroll
      for (int r = 0; r < 8; ++r) f[r] = *(const float4*)(p0 + (size_t)r * H_DIM);
      #pragma unroll
      for (int ii = 0; ii < 4; ++ii) {
        uint4 v;
        v.x = cvtpk((&f[0].x)[ii], (&f[1].x)[ii]);
        v.y = cvtpk((&f[2].x)[ii], (&f[3].x)[ii]);
        v.z = cvtpk((&f[4].x)[ii], (&f[5].x)[ii]);
        v.w = cvtpk((&f[6].x)[ii], (&f[7].x)[ii]);
        *(uint4*)(Bs + bwb[ii]) = v;
      }
    }
    __syncthreads();
    #pragma unroll
    for (int kk = 0; kk < 2; ++kk) {
      int xo = (kk * 4 + g4) << 4;
      short8v b[4];
      #pragma unroll
      for (int n = 0; n < 4; ++n)
        b[n] = *(const short8v*)(Bs + bro[n] + (xo ^ bsz[n]));
      #pragma unroll
      for (int m = 0; m < 8; ++m) {
        short8v a = *(const short8v*)(As + aoff[m] + (xo ^ la7_4));
        #pragma unroll
        for (int n = 0; n < 4; ++n)
          acc[m][n] = __builtin_amdgcn_mfma_f32_16x16x32_bf16(a, b[n], acc[m][n], 0, 0, 0);
      }
    }
    __syncthreads();
  }

  #pragma unroll
  for (int m = 0; m < 8; ++m) {
    #pragma unroll
    for (int r = 0; r < 4; ++r) {
      int row = wr + m * 16 + g4 * 4 + r;
      if (m0 + row < cntE) {
        int tok = rtok[base + m0 + row];
        float* orow = out + (size_t)tok * H_DIM + n0 + wc * 64;
        #pragma unroll
        for (int n = 0; n < 4; ++n)
          unsafeAtomicAdd(&orow[n * 16 + ln15], acc[m][n][r]);
      }
    }
  }
}

// ---------- launch ----------
extern "C" void kernel_launch(void* const* d_in, const int* in_sizes, int n_in,
                              void* d_out, int out_size, void* d_ws, size_t ws_size,
                              hipStream_t stream) {
  (void)in_sizes; (void)n_in;
  if (ws_size < WS_NEED) return;

  const float* x  = (const float*)d_in[0];
  const float* rw = (const float*)d_in[1];
  const float* wg = (const float*)d_in[2];
  const float* wu = (const float*)d_in[3];
  const float* wd = (const float*)d_in[4];
  float* out = (float*)d_out;
  float* logits = out + (size_t)T_TOK * H_DIM;

  char* ws = (char*)d_ws;
  u16* xb    = (u16*)(ws + OFF_XB);
  u16* abuf  = (u16*)(ws + OFF_ABUF);
  int* sel   = (int*)(ws + OFF_SEL);
  float* wts = (float*)(ws + OFF_WTS);
  int* cnt   = (int*)(ws + OFF_CNT);
  int* offs  = (int*)(ws + OFF_OFFS);
  int* curs  = (int*)(ws + OFF_CURS);
  int* rtok  = (int*)(ws + OFF_RTOK);
  float* rwt = (float*)(ws + OFF_RWT);
  int* mbe   = (int*)(ws + OFF_MBE);
  int* mbm0  = (int*)(ws + OFF_MBM0);
  int* mbn   = (int*)(ws + OFF_MBN);

  // out accumulated atomically -> zero every call
  hipMemsetAsync(d_out, 0, (size_t)out_size * sizeof(float), stream);
  hipMemsetAsync(ws + OFF_CNT, 0, 128, stream);

  cvt_x_kernel<<<(T_TOK * H_DIM / 8) / 256, 256, 0, stream>>>(x, xb);
  router_kernel<<<T_TOK / 4, 256, 0, stream>>>(x, rw, logits, sel, wts);
  hist_kernel<<<(T_TOK * TOPK) / 256, 256, 0, stream>>>(sel, cnt);
  prefix_kernel<<<1, 64, 0, stream>>>(cnt, offs, curs, mbe, mbm0, mbn);
  scatter_kernel<<<(T_TOK * TOPK) / 256, 256, 0, stream>>>(sel, wts, curs, rtok, rwt);
  gemm1k<<<dim3(I_DIM / 64, MBMAX), 256, 0, stream>>>(xb, wg, wu, cnt, offs, rtok, rwt, mbe, mbm0, mbn, abuf);
  gemm2k<<<dim3(H_DIM / 128, MBMAX), 256, 0, stream>>>(abuf, wd, cnt, offs, rtok, mbe, mbm0, mbn, out);
}